// Round 3
// baseline (76.208 us; speedup 1.0000x reference)
//
#include <hip/hip_runtime.h>

// Chamfer distance v2: B=4, N=M=4096, D=3, fp32 in, scalar fp32 out.
//
// R3: ONE dispatch. 512 blocks = 2 dirs x 4 batches x 64 held-tiles.
// Each block stages the FULL 4096-pt stream in LDS (64 KB, 2 blocks/CU,
// exactly 2 barriers), computes d2 = |h|^2 + (|c|^2 - 2 c.h) with stream
// pre-scaled to (-2x,-2y,-2z,|c|^2). Inner loop: 2 stream pts/iter/g ->
// 9 VALU per 2 pairs (v_min3). Cross-block combine via last-block-done:
// float ticket counter in ws (robust to ws init 0x00000000 *or* 0xAAAAAAAA
// poison: both are ~0.0f, finisher sees old > 510.5).

#define NPTS 4096
#define TILE 64     // held points per block
#define PHN  32     // phases (threads per held-group)
#define G    8      // held points per thread

__global__ __launch_bounds__(256, 2) void chamfer_fused(
    const float* __restrict__ coord, const float* __restrict__ gt,
    float* __restrict__ partials, float* __restrict__ counter,
    float* __restrict__ out)
{
    __shared__ float4 sc[NPTS];   // 64 KB exactly; tail scratch aliased below

    int bx   = blockIdx.x;
    int pass = bx >> 8;            // 0: held=gt/stream=coord, 1: reverse
    int r    = bx & 255;
    int b    = r >> 6;
    int tile = r & 63;

    const float* hbase = (pass ? coord : gt) + b * NPTS * 3;
    const float* sbase = (pass ? gt : coord) + b * NPTS * 3;

    int tid = threadIdx.x;
    int hg  = tid >> 5;            // 0..7 held group
    int ph  = tid & 31;            // 0..31 phase (xor<=16 stays in-half)

    // ---- stage ALL stream points as (-2x,-2y,-2z,|c|^2), coalesced ----
#pragma unroll
    for (int k = 0; k < NPTS / 256; ++k) {
        int p = k * 256 + tid;
        const float* s0 = sbase + p * 3;
        float x = s0[0], y = s0[1], z = s0[2];
        sc[p] = make_float4(-2.f * x, -2.f * y, -2.f * z, x * x + y * y + z * z);
    }

    // ---- held points -> registers ----
    float hx[G], hy[G], hz[G], h2[G], mn[G];
    int h0 = tile * TILE + hg * G;
#pragma unroll
    for (int g = 0; g < G; ++g) {
        float x = hbase[(h0 + g) * 3 + 0];
        float y = hbase[(h0 + g) * 3 + 1];
        float z = hbase[(h0 + g) * 3 + 2];
        hx[g] = x; hy[g] = y; hz[g] = z;
        h2[g] = x * x + y * y + z * z;
        mn[g] = INFINITY;
    }
    __syncthreads();

    // ---- main loop: 64 iters x (2 ds_read_b128 + 8x9 VALU) ----
#pragma unroll 4
    for (int it = 0; it < NPTS / (2 * PHN); ++it) {
        float4 c0 = sc[it * 64 + ph];
        float4 c1 = sc[it * 64 + 32 + ph];
#pragma unroll
        for (int g = 0; g < G; ++g) {
            float a = h2[g] + c0.w;
            a = fmaf(c0.x, hx[g], a);
            a = fmaf(c0.y, hy[g], a);
            a = fmaf(c0.z, hz[g], a);
            float d = h2[g] + c1.w;
            d = fmaf(c1.x, hx[g], d);
            d = fmaf(c1.y, hy[g], d);
            d = fmaf(c1.z, hz[g], d);
            mn[g] = fminf(fminf(a, d), mn[g]);   // v_min3_f32
        }
    }
    __syncthreads();   // all sc reads done; safe to alias tail scratch

    float* bsum  = reinterpret_cast<float*>(sc);        // [0..7]
    unsigned* fl = reinterpret_cast<unsigned*>(sc) + 8; // flag
    float* wred  = reinterpret_cast<float*>(sc) + 16;   // [16..19]

    // ---- min over 32 phases, sum over g ----
    float s = 0.f;
#pragma unroll
    for (int g = 0; g < G; ++g) {
        float v = mn[g];
        v = fminf(v, __shfl_xor(v, 16));
        v = fminf(v, __shfl_xor(v, 8));
        v = fminf(v, __shfl_xor(v, 4));
        v = fminf(v, __shfl_xor(v, 2));
        v = fminf(v, __shfl_xor(v, 1));
        s += fmaxf(v, 0.f);   // true d^2 >= 0; clamp fp cancellation
    }
    if (ph == 0) bsum[hg] = s;
    __syncthreads();

    if (tid == 0) {
        float t = 0.f;
#pragma unroll
        for (int i = 0; i < 8; ++i) t += bsum[i];
        __hip_atomic_store(&partials[bx], t, __ATOMIC_RELAXED, __HIP_MEMORY_SCOPE_AGENT);
        __threadfence();                         // release partials
        float old = atomicAdd(counter, 1.0f);    // device-scope ticket
        *fl = (old > 510.5f) ? 1u : 0u;          // init ~0 (0x00 or 0xAA poison)
    }
    __syncthreads();

    if (*fl) {                                   // last block: final reduce
        __threadfence();                         // acquire partials
        float s2 = 0.f;
#pragma unroll
        for (int k = 0; k < 2; ++k)
            s2 += __hip_atomic_load(&partials[k * 256 + tid],
                                    __ATOMIC_RELAXED, __HIP_MEMORY_SCOPE_AGENT);
#pragma unroll
        for (int off = 32; off > 0; off >>= 1)
            s2 += __shfl_down(s2, off);
        if ((tid & 63) == 0) wred[tid >> 6] = s2;
        __syncthreads();
        if (tid == 0)
            out[0] = (wred[0] + wred[1] + wred[2] + wred[3]) * (1.0f / 16384.0f);
    }
}

extern "C" void kernel_launch(void* const* d_in, const int* in_sizes, int n_in,
                              void* d_out, int out_size, void* d_ws, size_t ws_size,
                              hipStream_t stream) {
    const float* coord = (const float*)d_in[0];  // [4,4096,3]
    const float* gt    = (const float*)d_in[1];  // [4,4096,3]
    float* pf = (float*)d_ws;
    float* partials = pf;        // [512]
    float* counter  = pf + 512;  // 1 float ticket
    float* out = (float*)d_out;

    chamfer_fused<<<512, 256, 0, stream>>>(coord, gt, partials, counter, out);
}

// Round 4
// 70.495 us; speedup vs baseline: 1.0810x; 1.0810x over previous
//
#include <hip/hip_runtime.h>

// Chamfer distance v2: B=4, N=M=4096, D=3, fp32 in, scalar fp32 out.
//
// R4 = R2 skeleton (2 dispatches, chunked LDS double-buffer — measured faster
// than both the atomic-combine R1 and the fused R3) + two upgrades:
//  (1) fold |h|^2 out of the inner loop:
//        min_c d2 = h2 + min_c(|c|^2 - 2 c.h)
//      inner = 3 fma per stream pt + v_min3 per pair-of-pts = 7 VALU / 2 pairs.
//  (2) TILE 64->32: grid 1024 = 4 blocks/CU (R2 was grid-limited to 2),
//      16 waves/CU; phases=64 (full-wave shfl min-reduce).
// Stream staged as (-2x,-2y,-2z,|c|^2); consecutive ds_read_b128 pattern
// (canonical conflict-free per m134/m98).

#define NPTS 4096
#define TILE 32     // held points per block
#define PHN  64     // phases = threads per held-group (full wave)
#define G    8      // held points per thread
#define CH   512    // stream chunk
#define NCH  8      // NPTS / CH

__global__ __launch_bounds__(256, 4) void chamfer_pass(
    const float* __restrict__ coord, const float* __restrict__ gt,
    float* __restrict__ partials)
{
    __shared__ float4 sc[2][CH];   // 16 KB
    __shared__ float bsum[4];

    int bx   = blockIdx.x;
    int pass = bx >> 9;            // 0: held=gt/stream=coord, 1: reverse
    int r    = bx & 511;
    int b    = r >> 7;
    int tile = r & 127;            // 128 tiles of 32 held pts

    const float* hbase = (pass ? coord : gt) + b * NPTS * 3;
    const float* sbase = (pass ? gt : coord) + b * NPTS * 3;

    int tid = threadIdx.x;
    int hg  = tid >> 6;            // 0..3 held group
    int ph  = tid & 63;            // 0..63 phase (full wave)

    // ---- held points -> registers (broadcast across the wave) ----
    float hx[G], hy[G], hz[G], h2[G], mn[G];
    int h0 = tile * TILE + hg * G;
#pragma unroll
    for (int g = 0; g < G; ++g) {
        float x = hbase[(h0 + g) * 3 + 0];
        float y = hbase[(h0 + g) * 3 + 1];
        float z = hbase[(h0 + g) * 3 + 2];
        hx[g] = x; hy[g] = y; hz[g] = z;
        h2[g] = x * x + y * y + z * z;
        mn[g] = INFINITY;
    }

    // ---- stage chunk 0: (-2x,-2y,-2z,|c|^2) ----
    {
        int p = tid * 2;
        const float* s0 = sbase + p * 3;
        float x0 = s0[0], y0 = s0[1], z0 = s0[2];
        float x1 = s0[3], y1 = s0[4], z1 = s0[5];
        sc[0][p]     = make_float4(-2.f*x0, -2.f*y0, -2.f*z0, x0*x0 + y0*y0 + z0*z0);
        sc[0][p + 1] = make_float4(-2.f*x1, -2.f*y1, -2.f*z1, x1*x1 + y1*y1 + z1*z1);
    }
    __syncthreads();

    for (int ch = 0; ch < NCH; ++ch) {
        if (ch + 1 < NCH) {        // prefetch next chunk into other buffer
            int p = tid * 2;
            const float* s0 = sbase + ((ch + 1) * CH + p) * 3;
            float x0 = s0[0], y0 = s0[1], z0 = s0[2];
            float x1 = s0[3], y1 = s0[4], z1 = s0[5];
            int nb = (ch + 1) & 1;
            sc[nb][p]     = make_float4(-2.f*x0, -2.f*y0, -2.f*z0, x0*x0 + y0*y0 + z0*z0);
            sc[nb][p + 1] = make_float4(-2.f*x1, -2.f*y1, -2.f*z1, x1*x1 + y1*y1 + z1*z1);
        }

        const float4* cur = sc[ch & 1];
#pragma unroll
        for (int it = 0; it < CH / (2 * PHN); ++it) {   // 4 iters
            float4 c0 = cur[it * 128 + ph];
            float4 c1 = cur[it * 128 + 64 + ph];
#pragma unroll
            for (int g = 0; g < G; ++g) {
                float a = fmaf(c0.x, hx[g], c0.w);       // |c|^2 - 2 c.h
                a = fmaf(c0.y, hy[g], a);
                a = fmaf(c0.z, hz[g], a);
                float d = fmaf(c1.x, hx[g], c1.w);
                d = fmaf(c1.y, hy[g], d);
                d = fmaf(c1.z, hz[g], d);
                mn[g] = fminf(fminf(a, d), mn[g]);        // v_min3_f32
            }
        }
        __syncthreads();
    }

    // ---- min over 64 phases, add h2, sum over g ----
    float s = 0.f;
#pragma unroll
    for (int g = 0; g < G; ++g) {
        float v = mn[g];
        v = fminf(v, __shfl_xor(v, 32));
        v = fminf(v, __shfl_xor(v, 16));
        v = fminf(v, __shfl_xor(v, 8));
        v = fminf(v, __shfl_xor(v, 4));
        v = fminf(v, __shfl_xor(v, 2));
        v = fminf(v, __shfl_xor(v, 1));
        s += fmaxf(v + h2[g], 0.f);   // true d^2 >= 0; clamp fp cancellation
    }
    if (ph == 0) bsum[hg] = s;
    __syncthreads();
    if (tid == 0)
        partials[bx] = bsum[0] + bsum[1] + bsum[2] + bsum[3];
}

__global__ __launch_bounds__(256) void chamfer_final(
    const float* __restrict__ partials, float* __restrict__ out)
{
    __shared__ float wsum[4];
    int tid = threadIdx.x;
    float s = 0.f;
#pragma unroll
    for (int k = 0; k < 4; ++k)
        s += partials[k * 256 + tid];
#pragma unroll
    for (int off = 32; off > 0; off >>= 1)
        s += __shfl_down(s, off);
    if ((tid & 63) == 0) wsum[tid >> 6] = s;
    __syncthreads();
    if (tid == 0)
        out[0] = (wsum[0] + wsum[1] + wsum[2] + wsum[3]) * (1.0f / 16384.0f);
}

extern "C" void kernel_launch(void* const* d_in, const int* in_sizes, int n_in,
                              void* d_out, int out_size, void* d_ws, size_t ws_size,
                              hipStream_t stream) {
    const float* coord = (const float*)d_in[0];  // [4,4096,3]
    const float* gt    = (const float*)d_in[1];  // [4,4096,3]
    float* partials = (float*)d_ws;              // 1024 floats
    float* out = (float*)d_out;

    chamfer_pass<<<1024, 256, 0, stream>>>(coord, gt, partials);
    chamfer_final<<<1, 256, 0, stream>>>(partials, out);
}